// Round 6
// baseline (448.928 us; speedup 1.0000x reference)
//
#include <hip/hip_runtime.h>

#define BB 8
#define TT 2048
#define DD 768
#define EE 2304
#define MM (BB * TT)
#define MHK_ 768
#define LOG2E 1.44269504088896340736f

typedef __attribute__((ext_vector_type(8))) _Float16 f16x8;
typedef __attribute__((ext_vector_type(4))) float f32x4;

typedef const __attribute__((address_space(1))) void* gp_t;
typedef __attribute__((address_space(3))) void* lp_t;

__device__ __forceinline__ float fast_exp2(float x) { return __builtin_amdgcn_exp2f(x); }

// ---------- fused prep: zero l + x->f16 cast + tiled coalesced w transposes ----------
__global__ __launch_bounds__(256)
void k_prep(const float* __restrict__ x, const float* __restrict__ w_qkv,
            const float* __restrict__ w_out, _Float16* __restrict__ xh,
            _Float16* __restrict__ w_qkvT, _Float16* __restrict__ w_outT,
            float* __restrict__ lbuf) {
  __shared__ float tile[32][33];
  int bid = blockIdx.x;
  if (bid < 16) {
    lbuf[bid * 1024 + threadIdx.x * 4 + 0] = 0.f;
    lbuf[bid * 1024 + threadIdx.x * 4 + 1] = 0.f;
    lbuf[bid * 1024 + threadIdx.x * 4 + 2] = 0.f;
    lbuf[bid * 1024 + threadIdx.x * 4 + 3] = 0.f;
    return;
  }
  if (bid < 16 + 6144) {
    int idx = (bid - 16) * 256 + threadIdx.x;  // 8 f32 -> 8 f16 per thread
    const float4* p = (const float4*)(x + idx * 8);
    float4 a = p[0], b = p[1];
    f16x8 o;
    o[0] = (_Float16)a.x; o[1] = (_Float16)a.y; o[2] = (_Float16)a.z; o[3] = (_Float16)a.w;
    o[4] = (_Float16)b.x; o[5] = (_Float16)b.y; o[6] = (_Float16)b.z; o[7] = (_Float16)b.w;
    *(f16x8*)(xh + idx * 8) = o;
    return;
  }
  const float* in;
  _Float16* out;
  int R, C, t;
  if (bid < 6160 + 1728) {
    t = bid - 6160; in = w_qkv; out = w_qkvT; R = DD; C = EE;   // tiles: 24 x 72
  } else {
    t = bid - 7888; in = w_out; out = w_outT; R = DD; C = DD;   // tiles: 24 x 24
  }
  const int tpr = C / 32;
  const int r0 = (t / tpr) * 32, c0 = (t - (t / tpr) * tpr) * 32;
  const int tx = threadIdx.x & 31, ty = threadIdx.x >> 5;
  for (int k = 0; k < 4; k++)
    tile[ty + k * 8][tx] = in[(size_t)(r0 + ty + k * 8) * C + c0 + tx];
  __syncthreads();
  for (int k = 0; k < 4; k++)
    out[(size_t)(c0 + ty + k * 8) * R + r0 + tx] = (_Float16)tile[tx][ty + k * 8];
}

// ---------- V columns of qkv -> Vt[b][d][t] ----------
__global__ __launch_bounds__(256)
void k_vt(const _Float16* __restrict__ qkv, _Float16* __restrict__ Vt) {
  __shared__ _Float16 tile[32][33];
  const int tx = threadIdx.x & 31;
  const int ty = threadIdx.x >> 5;
  const int t0 = blockIdx.x * 32;
  const int d0 = blockIdx.y * 32;
  const int b = blockIdx.z;
  for (int r = 0; r < 4; r++) {
    int t = t0 + ty + r * 8;
    tile[ty + r * 8][tx] = qkv[(size_t)(b * TT + t) * EE + 2 * MHK_ + d0 + tx];
  }
  __syncthreads();
  for (int r = 0; r < 4; r++) {
    int d = d0 + ty + r * 8;
    Vt[((size_t)b * DD + d) * TT + t0 + tx] = tile[tx][ty + r * 8];
  }
}

// ---------- MFMA GEMM: C[M,N] = A[M,K] * Bt[N,K]^T ----------
// 256x256 tile, BK=32, 512 thr = 8 waves (2m x 4n), per-wave out 128x64
// (acc[8][4]). Rationale: rounds 0-5 showed all GEMMs pinned at ~8-9 TB/s of
// L2-fill traffic (shape-independent) with every CU pipe <25% -> external-BW
// bound. 256^2 halves fetched bytes per MFMA (128 B/MFMA vs 256).
// Loop structure = round-5 verified: TRIPLE-buffered glds staging, counted
// vmcnt (never drains in main loop):
//   prologue stages tiles 0,1; iter t: vmcnt(4) [tile t retired, t+1 in
//   flight] ; s_barrier ; sched_barrier ; stage tile t+2 into slot (t+2)%3 ;
//   ds_read slot t%3 ; 64 MFMA (two af half-groups to cap live VGPRs).
//   Final iter vmcnt(0). WAR safe: slot (t+2)%3 last read in iter t-1, reads
//   complete (lgkm) before that wave's MFMA which precedes the iter-t barrier.
// Staging identical arithmetic to 128^2 (4 glds/thread/tile: 512 thr x 16B =
// 8KB = 128 rows/instr, 2 instr per 256-row operand).
// Chunk swizzle (verified 0 conflicts rounds 3/5): LDS[row][slot] holds global
// k-chunk slot^((row>>1)&3); staging source chunk (tid&3)^((tid>>3)&3); reads
// quad^((l16>>1)&3). Row stride 64B unchanged; wm*128/i*16 don't touch row
// bits 1-2, so the involution carries over exactly.
// Epilogue modes: QKV (bias+Q log2-scale), S (P=exp2(s-24)+atomic row sums),
// PV (row scale 1/l), OUT (bias, f32).
template<bool OUT_F16, bool HAS_BIAS, bool QSCALE, bool EXP_LSUM, bool ROWSCALE>
__global__ __launch_bounds__(512, 2)
void k_gemm(const _Float16* __restrict__ A, const _Float16* __restrict__ Bt,
            const float* __restrict__ bias, void* __restrict__ Cv,
            float* __restrict__ lbuf,
            int lda, int ldb, int ldc, int Kd,
            long long strideA, long long strideB, long long strideC,
            int gx, int gyp, float qscale) {
  __shared__ __align__(16) _Float16 As[3][256 * 32];
  __shared__ __align__(16) _Float16 Bs[3][256 * 32];
  const int tid = threadIdx.x;
  const int lane = tid & 63;
  const int w = tid >> 6;        // 0..7
  const int wm = w >> 2;         // 0..1 -> row half (128)
  const int wn = w & 3;          // 0..3 -> col quarter (64)
  const int quad = lane >> 4;
  const int l16 = lane & 15;

  // XCD-aware decode of flattened block id
  const int bid = blockIdx.x;
  const int xcd = bid & 7;
  int local = bid >> 3;
  const int perz = gx * gyp;
  const int z = local / perz;
  local -= z * perz;
  const int lm = local / gx;
  const int nblk = local - lm * gx;
  const int m0 = (xcd * gyp + lm) * 256;
  const int n0 = nblk * 256;

  // staging lane offsets: row = tid>>2 (128 rows/instr), chunk (tid&3)^((tid>>3)&3)
  const int srow = tid >> 2;
  const int scc = ((tid & 3) ^ ((tid >> 3) & 3)) * 8;
  const _Float16* Abase = A + (long long)z * strideA + (size_t)(m0 + srow) * lda + scc;
  const _Float16* Bbase = Bt + (long long)z * strideB + (size_t)(n0 + srow) * ldb + scc;
  const size_t a128 = (size_t)128 * lda;
  const size_t b128 = (size_t)128 * ldb;
  const int wb0 = (w * 16) * 32;          // rows 0-127 group dest (f16 idx)
  const int wb1 = (128 + w * 16) * 32;    // rows 128-255 group dest

  f32x4 acc[8][4];
#pragma unroll
  for (int i = 0; i < 8; i++)
#pragma unroll
    for (int j = 0; j < 4; j++)
#pragma unroll
      for (int r = 0; r < 4; r++) acc[i][j][r] = 0.f;

  const int fsw = (quad ^ ((l16 >> 1) & 3)) * 8;  // fragment k-chunk slot

#define STG(slot, t) do { \
    const size_t ko_ = (size_t)(t) * 32; \
    __builtin_amdgcn_global_load_lds((gp_t)(Abase + ko_), (lp_t)(&As[slot][wb0]), 16, 0, 0); \
    __builtin_amdgcn_global_load_lds((gp_t)(Abase + ko_ + a128), (lp_t)(&As[slot][wb1]), 16, 0, 0); \
    __builtin_amdgcn_global_load_lds((gp_t)(Bbase + ko_), (lp_t)(&Bs[slot][wb0]), 16, 0, 0); \
    __builtin_amdgcn_global_load_lds((gp_t)(Bbase + ko_ + b128), (lp_t)(&Bs[slot][wb1]), 16, 0, 0); \
  } while (0)

  const int niter = Kd >> 5;  // 24 or 64 at all call sites
  STG(0, 0);
  STG(1, 1);

  int rs = 0;   // read slot  = t % 3
  int wsl = 2;  // write slot = (t+2) % 3
  for (int it = 0; it < niter; it++) {
    if (it + 1 < niter)
      asm volatile("s_waitcnt vmcnt(4)" ::: "memory");   // tile t retired, t+1 in flight
    else
      asm volatile("s_waitcnt vmcnt(0)" ::: "memory");   // last tile must land
    __builtin_amdgcn_s_barrier();
    __builtin_amdgcn_sched_barrier(0);
    if (it + 2 < niter) STG(wsl, it + 2);
    f16x8 bf[4];
#pragma unroll
    for (int j = 0; j < 4; j++)
      bf[j] = *(const f16x8*)&Bs[rs][(wn * 64 + j * 16 + l16) * 32 + fsw];
    {
      f16x8 af[4];
#pragma unroll
      for (int i = 0; i < 4; i++)
        af[i] = *(const f16x8*)&As[rs][(wm * 128 + i * 16 + l16) * 32 + fsw];
#pragma unroll
      for (int i = 0; i < 4; i++)
#pragma unroll
        for (int j = 0; j < 4; j++)
          acc[i][j] = __builtin_amdgcn_mfma_f32_16x16x32_f16(af[i], bf[j], acc[i][j], 0, 0, 0);
    }
    {
      f16x8 af[4];
#pragma unroll
      for (int i = 0; i < 4; i++)
        af[i] = *(const f16x8*)&As[rs][(wm * 128 + (i + 4) * 16 + l16) * 32 + fsw];
#pragma unroll
      for (int i = 0; i < 4; i++)
#pragma unroll
        for (int j = 0; j < 4; j++)
          acc[i + 4][j] = __builtin_amdgcn_mfma_f32_16x16x32_f16(af[i], bf[j], acc[i + 4][j], 0, 0, 0);
    }
    rs = (rs == 2) ? 0 : rs + 1;
    wsl = (wsl == 2) ? 0 : wsl + 1;
  }

  const long long cbase = (long long)z * strideC;
  const int rowbb = m0 + wm * 128;
  const int colbb = n0 + wn * 64;

  if (EXP_LSUM) {
    float psum[8][4];
#pragma unroll
    for (int i = 0; i < 8; i++)
#pragma unroll
      for (int r = 0; r < 4; r++) psum[i][r] = 0.f;
#pragma unroll
    for (int j = 0; j < 4; j++) {
      int col = colbb + j * 16 + l16;
#pragma unroll
      for (int i = 0; i < 8; i++) {
        int row = rowbb + i * 16 + quad * 4;
#pragma unroll
        for (int r = 0; r < 4; r++) {
          float p = fast_exp2(acc[i][j][r] - 24.f);
          psum[i][r] += p;
          ((_Float16*)Cv)[cbase + (size_t)(row + r) * ldc + col] = (_Float16)p;
        }
      }
    }
#pragma unroll
    for (int i = 0; i < 8; i++)
#pragma unroll
      for (int r = 0; r < 4; r++) {
        float v = psum[i][r];
        v += __shfl_xor(v, 1, 64);
        v += __shfl_xor(v, 2, 64);
        v += __shfl_xor(v, 4, 64);
        v += __shfl_xor(v, 8, 64);
        if (l16 == 0)
          atomicAdd(&lbuf[z * TT + rowbb + i * 16 + quad * 4 + r], v);
      }
    return;
  }

  float invr[8][4];
  if (ROWSCALE) {
#pragma unroll
    for (int i = 0; i < 8; i++)
#pragma unroll
      for (int r = 0; r < 4; r++)
        invr[i][r] = 1.f / lbuf[z * TT + rowbb + i * 16 + quad * 4 + r];
  }

#pragma unroll
  for (int j = 0; j < 4; j++) {
    int col = colbb + j * 16 + l16;
    float bv = HAS_BIAS ? bias[col] : 0.f;
    float sc = 1.f;
    if (QSCALE && col < MHK_) sc = qscale;
#pragma unroll
    for (int i = 0; i < 8; i++) {
      int row = rowbb + i * 16 + quad * 4;
#pragma unroll
      for (int r = 0; r < 4; r++) {
        float v = (acc[i][j][r] + bv) * sc;
        if (ROWSCALE) v = acc[i][j][r] * invr[i][r];
        if (OUT_F16)
          ((_Float16*)Cv)[cbase + (size_t)(row + r) * ldc + col] = (_Float16)v;
        else
          ((float*)Cv)[cbase + (size_t)(row + r) * ldc + col] = v;
      }
    }
  }
}

extern "C" void kernel_launch(void* const* d_in, const int* in_sizes, int n_in,
                              void* d_out, int out_size, void* d_ws, size_t ws_size,
                              hipStream_t stream) {
  const float* x = (const float*)d_in[0];
  const float* w_qkv = (const float*)d_in[1];
  const float* b_qkv = (const float*)d_in[2];
  const float* w_out = (const float*)d_in[3];
  const float* b_out = (const float*)d_in[4];

  _Float16* ws = (_Float16*)d_ws;
  _Float16* w_qkvT = ws;                         // [2304][768]
  _Float16* w_outT = w_qkvT + (size_t)EE * DD;   // [768][768]
  _Float16* qkv = w_outT + (size_t)DD * DD;      // [16384][2304]  (Q pre-scaled)
  _Float16* Vt = qkv + (size_t)MM * EE;          // [8][768][2048]
  _Float16* P = Vt + (size_t)BB * DD * TT;       // [8][2048][2048] = exp2(S-24)
  _Float16* ctx = P + (size_t)BB * TT * TT;      // [16384][768]
  float* lbuf = (float*)(ctx + (size_t)MM * DD); // [16384] row sums
  _Float16* xh = ctx + (size_t)MM * DD + MM * 2; // x-f16 after lbuf

  // 0. fused prep (l zero + x cast + tiled weight transposes)
  k_prep<<<8464, 256, 0, stream>>>(x, w_qkv, w_out, xh, w_qkvT, w_outT, lbuf);
  // 1. qkv projection (+bias, Q scaled into log2 domain)  [256x256, 576 blocks]
  k_gemm<true, true, true, false, false><<<576, 512, 0, stream>>>(
      xh, w_qkvT, b_qkv, qkv, nullptr, DD, DD, EE, DD, 0, 0, 0, 9, 8, 0.125f * LOG2E);
  // 2. V -> Vt
  k_vt<<<dim3(TT / 32, DD / 32, BB), 256, 0, stream>>>(qkv, Vt);
  // 3. P = exp2(Q K^T - 24) + row sums (batched)  [256x256, 512 blocks]
  k_gemm<true, false, false, true, false><<<512, 512, 0, stream>>>(
      qkv, qkv + MHK_, nullptr, P, lbuf, EE, EE, TT, DD,
      (long long)TT * EE, (long long)TT * EE, (long long)TT * TT, 8, 1, 1.f);
  // 4. ctx = (P V) / l (batched)  [256x256, 192 blocks]
  k_gemm<true, false, false, false, true><<<192, 512, 0, stream>>>(
      P, Vt, nullptr, ctx, lbuf, TT, TT, DD, TT,
      (long long)TT * TT, (long long)DD * TT, (long long)TT * DD, 3, 1, 1.f);
  // 5. out = ctx w_out + b_out (fp32)  [256x256, 192 blocks]
  k_gemm<false, true, false, false, false><<<192, 512, 0, stream>>>(
      ctx, w_outT, b_out, d_out, nullptr, DD, DD, DD, DD, 0, 0, 0, 3, 8, 1.f);
}

// Round 8
// 381.840 us; speedup vs baseline: 1.1757x; 1.1757x over previous
//
#include <hip/hip_runtime.h>

#define BB 8
#define TT 2048
#define DD 768
#define EE 2304
#define MM (BB * TT)
#define MHK_ 768
#define LOG2E 1.44269504088896340736f

typedef __attribute__((ext_vector_type(8))) _Float16 f16x8;
typedef __attribute__((ext_vector_type(4))) float f32x4;

typedef const __attribute__((address_space(1))) void* gp_t;
typedef __attribute__((address_space(3))) void* lp_t;

__device__ __forceinline__ float fast_exp2(float x) { return __builtin_amdgcn_exp2f(x); }

// ---------- fused prep: zero l + x->f16 cast + tiled coalesced w transposes ----------
__global__ __launch_bounds__(256)
void k_prep(const float* __restrict__ x, const float* __restrict__ w_qkv,
            const float* __restrict__ w_out, _Float16* __restrict__ xh,
            _Float16* __restrict__ w_qkvT, _Float16* __restrict__ w_outT,
            float* __restrict__ lbuf) {
  __shared__ float tile[32][33];
  int bid = blockIdx.x;
  if (bid < 16) {
    lbuf[bid * 1024 + threadIdx.x * 4 + 0] = 0.f;
    lbuf[bid * 1024 + threadIdx.x * 4 + 1] = 0.f;
    lbuf[bid * 1024 + threadIdx.x * 4 + 2] = 0.f;
    lbuf[bid * 1024 + threadIdx.x * 4 + 3] = 0.f;
    return;
  }
  if (bid < 16 + 6144) {
    int idx = (bid - 16) * 256 + threadIdx.x;  // 8 f32 -> 8 f16 per thread
    const float4* p = (const float4*)(x + idx * 8);
    float4 a = p[0], b = p[1];
    f16x8 o;
    o[0] = (_Float16)a.x; o[1] = (_Float16)a.y; o[2] = (_Float16)a.z; o[3] = (_Float16)a.w;
    o[4] = (_Float16)b.x; o[5] = (_Float16)b.y; o[6] = (_Float16)b.z; o[7] = (_Float16)b.w;
    *(f16x8*)(xh + idx * 8) = o;
    return;
  }
  const float* in;
  _Float16* out;
  int R, C, t;
  if (bid < 6160 + 1728) {
    t = bid - 6160; in = w_qkv; out = w_qkvT; R = DD; C = EE;   // tiles: 24 x 72
  } else {
    t = bid - 7888; in = w_out; out = w_outT; R = DD; C = DD;   // tiles: 24 x 24
  }
  const int tpr = C / 32;
  const int r0 = (t / tpr) * 32, c0 = (t - (t / tpr) * tpr) * 32;
  const int tx = threadIdx.x & 31, ty = threadIdx.x >> 5;
  for (int k = 0; k < 4; k++)
    tile[ty + k * 8][tx] = in[(size_t)(r0 + ty + k * 8) * C + c0 + tx];
  __syncthreads();
  for (int k = 0; k < 4; k++)
    out[(size_t)(c0 + ty + k * 8) * R + r0 + tx] = (_Float16)tile[tx][ty + k * 8];
}

// ---------- MFMA GEMM (verified round-5 loop): C[M,N] = A[M,K] * Bt[N,K]^T ----------
// 128x128 tile, BK=32, 4 waves, TRIPLE-buffered glds staging with COUNTED vmcnt:
//   prologue stages tiles 0,1; iter t: vmcnt(4) [tile t retired, t+1 stays in
//   flight across the barrier]; s_barrier; sched_barrier; stage tile t+2 into
//   slot (t+2)%3; ds_read slot t%3; 16 MFMA. Final iter vmcnt(0).
// Chunk swizzle (verified 0 bank conflicts): LDS[row][slot] holds global
// k-chunk slot^((row>>1)&3); staging source chunk (tid&3)^((tid>>3)&3);
// fragment reads quad^((l16>>1)&3).
// Decode: gyp>0 -> XCD-grouped (m-tiles = 8*gyp per batch); gyp<0 -> linear
// (m-tiles = -gyp per batch; for M not divisible by 8 tiles, e.g. VWt M=768).
// Epilogue modes: QKV (bias + Q log2-scale), S (P=exp2(s-24) + atomic row
// sums), PVW (rowscale 1/l THEN +bias, f32 out), plain f16 (VWt).
template<bool OUT_F16, bool HAS_BIAS, bool QSCALE, bool EXP_LSUM, bool ROWSCALE>
__global__ __launch_bounds__(256)
void k_gemm(const _Float16* __restrict__ A, const _Float16* __restrict__ Bt,
            const float* __restrict__ bias, void* __restrict__ Cv,
            float* __restrict__ lbuf,
            int lda, int ldb, int ldc, int Kd,
            long long strideA, long long strideB, long long strideC,
            int gx, int gyp, float qscale) {
  __shared__ __align__(16) _Float16 As[3][128 * 32];
  __shared__ __align__(16) _Float16 Bs[3][128 * 32];
  const int tid = threadIdx.x;
  const int lane = tid & 63;
  const int w = tid >> 6;
  const int quad = lane >> 4;
  const int l16 = lane & 15;

  const int bid = blockIdx.x;
  int m0, n0, z;
  if (gyp > 0) {  // XCD-grouped: m-tile = xcd*gyp + lm
    const int xcd = bid & 7;
    int local = bid >> 3;
    const int perz = gx * gyp;
    z = local / perz;
    local -= z * perz;
    const int lm = local / gx;
    m0 = (xcd * gyp + lm) * 128;
    n0 = (local - lm * gx) * 128;
  } else {        // linear: -gyp m-tiles per batch (M not 8-tile divisible)
    const int mt = -gyp;
    const int perz = gx * mt;
    z = bid / perz;
    int local = bid - z * perz;
    const int lm = local / gx;
    m0 = lm * 128;
    n0 = (local - lm * gx) * 128;
  }

  const int wr = (w >> 1) * 64;
  const int wc = (w & 1) * 64;

  const int srow = tid >> 2;
  const int scc = ((tid & 3) ^ ((tid >> 3) & 3)) * 8;
  const _Float16* Abase = A + (long long)z * strideA + (size_t)(m0 + srow) * lda + scc;
  const _Float16* Bbase = Bt + (long long)z * strideB + (size_t)(n0 + srow) * ldb + scc;
  const size_t a64 = (size_t)64 * lda;
  const size_t b64 = (size_t)64 * ldb;
  const int wbase = (w * 16) * 32;

  f32x4 acc[4][4];
  for (int i = 0; i < 4; i++)
    for (int j = 0; j < 4; j++)
      for (int r = 0; r < 4; r++) acc[i][j][r] = 0.f;

  const int fsw = (quad ^ ((l16 >> 1) & 3)) * 8;

#define STG(slot, t) do { \
    const size_t ko_ = (size_t)(t) * 32; \
    __builtin_amdgcn_global_load_lds((gp_t)(Abase + ko_), (lp_t)(&As[slot][wbase]), 16, 0, 0); \
    __builtin_amdgcn_global_load_lds((gp_t)(Abase + ko_ + a64), (lp_t)(&As[slot][wbase + 64 * 32]), 16, 0, 0); \
    __builtin_amdgcn_global_load_lds((gp_t)(Bbase + ko_), (lp_t)(&Bs[slot][wbase]), 16, 0, 0); \
    __builtin_amdgcn_global_load_lds((gp_t)(Bbase + ko_ + b64), (lp_t)(&Bs[slot][wbase + 64 * 32]), 16, 0, 0); \
  } while (0)

  const int niter = Kd >> 5;  // >= 24 at all call sites
  STG(0, 0);
  STG(1, 1);

  int rs = 0;
  int wsl = 2;
  for (int it = 0; it < niter; it++) {
    if (it + 1 < niter)
      asm volatile("s_waitcnt vmcnt(4)" ::: "memory");
    else
      asm volatile("s_waitcnt vmcnt(0)" ::: "memory");
    __builtin_amdgcn_s_barrier();
    __builtin_amdgcn_sched_barrier(0);
    if (it + 2 < niter) STG(wsl, it + 2);
    f16x8 af[4], bf[4];
    for (int i = 0; i < 4; i++) af[i] = *(const f16x8*)&As[rs][(wr + i * 16 + l16) * 32 + fsw];
    for (int j = 0; j < 4; j++) bf[j] = *(const f16x8*)&Bs[rs][(wc + j * 16 + l16) * 32 + fsw];
    for (int i = 0; i < 4; i++)
      for (int j = 0; j < 4; j++)
        acc[i][j] = __builtin_amdgcn_mfma_f32_16x16x32_f16(af[i], bf[j], acc[i][j], 0, 0, 0);
    rs = (rs == 2) ? 0 : rs + 1;
    wsl = (wsl == 2) ? 0 : wsl + 1;
  }
#undef STG

  const long long cbase = (long long)z * strideC;

  if (EXP_LSUM) {
    float psum[4][4];
    for (int i = 0; i < 4; i++)
      for (int r = 0; r < 4; r++) psum[i][r] = 0.f;
    for (int j = 0; j < 4; j++) {
      int col = n0 + wc + j * 16 + l16;
      for (int i = 0; i < 4; i++) {
        int row = m0 + wr + i * 16 + quad * 4;
        for (int r = 0; r < 4; r++) {
          float p = fast_exp2(acc[i][j][r] - 24.f);
          psum[i][r] += p;
          ((_Float16*)Cv)[cbase + (size_t)(row + r) * ldc + col] = (_Float16)p;
        }
      }
    }
    for (int i = 0; i < 4; i++)
      for (int r = 0; r < 4; r++) {
        float v = psum[i][r];
        v += __shfl_xor(v, 1, 64);
        v += __shfl_xor(v, 2, 64);
        v += __shfl_xor(v, 4, 64);
        v += __shfl_xor(v, 8, 64);
        if (l16 == 0)
          atomicAdd(&lbuf[z * TT + m0 + wr + i * 16 + quad * 4 + r], v);
      }
    return;
  }

  float invr[4][4];
  if (ROWSCALE) {
    for (int i = 0; i < 4; i++)
      for (int r = 0; r < 4; r++)
        invr[i][r] = 1.f / lbuf[z * TT + m0 + wr + i * 16 + quad * 4 + r];
  }

  for (int j = 0; j < 4; j++) {
    int col = n0 + wc + j * 16 + l16;
    float bv = HAS_BIAS ? bias[col] : 0.f;
    float sc = 1.f;
    if (QSCALE && col < MHK_) sc = qscale;
    for (int i = 0; i < 4; i++) {
      int row = m0 + wr + i * 16 + quad * 4;
      for (int r = 0; r < 4; r++) {
        // ROWSCALE composes with bias: (acc/l) + b  (used by fused PVW epilogue)
        float v = ROWSCALE ? (acc[i][j][r] * invr[i][r] + bv)
                           : ((acc[i][j][r] + bv) * sc);
        if (OUT_F16)
          ((_Float16*)Cv)[cbase + (size_t)(row + r) * ldc + col] = (_Float16)v;
        else
          ((float*)Cv)[cbase + (size_t)(row + r) * ldc + col] = v;
      }
    }
  }
}

extern "C" void kernel_launch(void* const* d_in, const int* in_sizes, int n_in,
                              void* d_out, int out_size, void* d_ws, size_t ws_size,
                              hipStream_t stream) {
  const float* x = (const float*)d_in[0];
  const float* w_qkv = (const float*)d_in[1];
  const float* b_qkv = (const float*)d_in[2];
  const float* w_out = (const float*)d_in[3];
  const float* b_out = (const float*)d_in[4];

  _Float16* ws = (_Float16*)d_ws;
  _Float16* w_qkvT = ws;                         // [2304][768]
  _Float16* w_outT = w_qkvT + (size_t)EE * DD;   // [768][768]  (= w_out^T)
  _Float16* qkv = w_outT + (size_t)DD * DD;      // [16384][2304]  (Q pre-scaled)
  _Float16* VWt = qkv + (size_t)MM * EE;         // [8][768][2048] = (V w_out)^T per batch
  _Float16* P = VWt + (size_t)BB * DD * TT;      // [8][2048][2048] = exp2(S-24)
  _Float16* ctx = P + (size_t)BB * TT * TT;      // (unused; layout kept)
  float* lbuf = (float*)(ctx + (size_t)MM * DD); // [16384] row sums
  _Float16* xh = ctx + (size_t)MM * DD + MM * 2; // x-f16 after lbuf

  // 0. fused prep (l zero + x cast + tiled weight transposes)
  k_prep<<<8464, 256, 0, stream>>>(x, w_qkv, w_out, xh, w_qkvT, w_outT, lbuf);
  // 1. qkv projection (+bias, Q scaled into log2 domain)  [128x128, 2304 blocks]
  k_gemm<true, true, true, false, false><<<2304, 256, 0, stream>>>(
      xh, w_qkvT, b_qkv, qkv, nullptr, DD, DD, EE, DD, 0, 0, 0, 18, 16, 0.125f * LOG2E);
  // 2. VWt[z][d][t] = (V w_out)^T: A = w_outT rows (d_out), Bt = V rows of qkv.
  //    out = ((P V)/l) W + b  ==  (P (V W))/l + b  -- 1/l commutes with right-mul.
  //    Replaces k_vt AND the out-projection GEMM; output is already in Bt
  //    layout for step 4.  [128x128, 6x16x8 = 768 blocks, linear decode]
  k_gemm<true, false, false, false, false><<<768, 256, 0, stream>>>(
      w_outT, qkv + 2 * MHK_, nullptr, VWt, nullptr, DD, EE, TT, DD,
      0, (long long)TT * EE, (long long)DD * TT, 16, -6, 1.f);
  // 3. P = exp2(Q K^T - 24) + row sums (batched, full 768-d contraction)
  //    [128x128, 2048 blocks]
  k_gemm<true, false, false, true, false><<<2048, 256, 0, stream>>>(
      qkv, qkv + MHK_, nullptr, P, lbuf, EE, EE, TT, DD,
      (long long)TT * EE, (long long)TT * EE, (long long)TT * TT, 16, 2, 1.f);
  // 4. out = P VWt / l + b_out (batched, f32)  [128x128, 768 blocks]
  k_gemm<false, true, false, false, true><<<768, 256, 0, stream>>>(
      P, VWt, b_out, d_out, lbuf, TT, TT, DD, TT,
      (long long)TT * TT, (long long)DD * TT, (long long)TT * DD, 6, 2, 1.f);
}